// Round 1
// baseline (160.935 us; speedup 1.0000x reference)
//
#include <hip/hip_runtime.h>
#include <math.h>

#define LN_EPS 1e-5f

// Problem: B=8 scenes, A=16 agents, L=80 lanes, D=128, H=6.
// N=768 nodes (128 agents first), 96 nodes/scene, dense per-scene attention.
// ws layout (floats): KV[768][1536] | Qb[128][768] | AO[128][768]

// ---------------------------------------------------------------------------
// Kernel 1: KV = nodes @ [Wk | relu?no->raw K | Wv(relu applied)] , Qb = agents @ Wq
// Block tile 64 rows x 128 cols, 256 threads, 4x8 per thread.
// A staged k-major in LDS (broadcast b128 reads, conflict-free); B from global.
__global__ __launch_bounds__(256) void k_gemm_qkv(
    const float* __restrict__ agents, const float* __restrict__ lanes,
    const float* __restrict__ Wq, const float* __restrict__ Wk,
    const float* __restrict__ Wv, float* __restrict__ KV, float* __restrict__ Qb)
{
    __shared__ float Ast[128][64];  // [k][row]

    const int tid = threadIdx.x;
    const int bid = blockIdx.x;

    const float* W;
    float* Out;
    int r0, wc0, dc0, dstride;
    bool dorelu = false;
    if (bid < 144) {                       // KV part: 12 row-blocks x 12 col-blocks
        const int br = bid % 12, bc = bid / 12;
        r0 = br * 64;
        if (bc < 6) { W = Wk; wc0 = bc * 128; dorelu = false; }
        else        { W = Wv; wc0 = (bc - 6) * 128; dorelu = true; }
        Out = KV; dc0 = bc * 128; dstride = 1536;
    } else {                               // Q part: 2 row-blocks x 6 col-blocks
        const int idx = bid - 144;
        const int br = idx & 1, bc = idx >> 1;
        r0 = br * 64;
        W = Wq; wc0 = bc * 128; dorelu = false;
        Out = Qb; dc0 = wc0; dstride = 768;
    }

    // stage A tile (64 rows x 128 k), transposed into Ast[k][row]
    {
        const int row = tid >> 2;      // 0..63
        const int kv = tid & 3;        // 0..3
        const int gr = r0 + row;
        const float* src = (gr < 128) ? (agents + gr * 128) : (lanes + (size_t)(gr - 128) * 128);
        #pragma unroll
        for (int j = 0; j < 8; ++j) {
            const int k0 = kv * 4 + j * 16;
            const float4 a = *(const float4*)(src + k0);
            Ast[k0 + 0][row] = a.x;
            Ast[k0 + 1][row] = a.y;
            Ast[k0 + 2][row] = a.z;
            Ast[k0 + 3][row] = a.w;
        }
    }
    __syncthreads();

    const int tx = tid & 15;    // cols 8*tx .. 8*tx+7
    const int ty = tid >> 4;    // rows 4*ty .. 4*ty+3
    const float* wp = W + wc0 + tx * 8;

    float acc[4][8] = {};
    #pragma unroll 4
    for (int k = 0; k < 128; ++k) {
        const float4 a  = *(const float4*)&Ast[k][ty * 4];
        const float4 b0 = *(const float4*)(wp + (size_t)k * 768);
        const float4 b1 = *(const float4*)(wp + (size_t)k * 768 + 4);
        const float av[4] = {a.x, a.y, a.z, a.w};
        #pragma unroll
        for (int i = 0; i < 4; ++i) {
            acc[i][0] += av[i] * b0.x; acc[i][1] += av[i] * b0.y;
            acc[i][2] += av[i] * b0.z; acc[i][3] += av[i] * b0.w;
            acc[i][4] += av[i] * b1.x; acc[i][5] += av[i] * b1.y;
            acc[i][6] += av[i] * b1.z; acc[i][7] += av[i] * b1.w;
        }
    }

    #pragma unroll
    for (int i = 0; i < 4; ++i) {
        const int r = r0 + ty * 4 + i;
        float v[8];
        #pragma unroll
        for (int c = 0; c < 8; ++c) v[c] = dorelu ? fmaxf(acc[i][c], 0.0f) : acc[i][c];
        float* dst = Out + (size_t)r * dstride + dc0 + tx * 8;
        *(float4*)(dst)     = make_float4(v[0], v[1], v[2], v[3]);
        *(float4*)(dst + 4) = make_float4(v[4], v[5], v[6], v[7]);
    }
}

// ---------------------------------------------------------------------------
// Kernel 2: per (scene, head) attention. 48 blocks x 256 threads.
__global__ __launch_bounds__(256) void k_attn(
    const float* __restrict__ KV, const float* __restrict__ Qb, float* __restrict__ AO)
{
    __shared__ float Qs[16][128];
    __shared__ float Buf[96][128];   // holds K, then reused for V
    __shared__ float Sm[16][96];

    const int tid = threadIdx.x;
    const int s = blockIdx.x / 6;
    const int h = blockIdx.x % 6;

    // load Q rows (agents of scene s, head h)
    for (int idx = tid; idx < 16 * 32; idx += 256) {
        const int i = idx >> 5, dv = idx & 31;
        *(float4*)&Qs[i][dv * 4] =
            *(const float4*)(Qb + (size_t)(s * 16 + i) * 768 + h * 128 + dv * 4);
    }
    // load K rows (96 scene nodes)
    for (int idx = tid; idx < 96 * 32; idx += 256) {
        const int n = idx >> 5, dv = idx & 31;
        const int g = (n < 16) ? (s * 16 + n) : (128 + s * 80 + (n - 16));
        *(float4*)&Buf[n][dv * 4] =
            *(const float4*)(KV + (size_t)g * 1536 + h * 128 + dv * 4);
    }
    __syncthreads();

    // scores: S[i][j] = scale * Q[i].K[j]; 2x4 per thread, 192 threads
    if (tid < 192) {
        const int jg = tid % 24, ig = tid / 24;
        const int j0 = jg * 4, i0 = ig * 2;
        float a00=0,a01=0,a02=0,a03=0,a10=0,a11=0,a12=0,a13=0;
        #pragma unroll 4
        for (int kk = 0; kk < 32; ++kk) {
            const float4 q0  = *(const float4*)&Qs[i0][kk * 4];
            const float4 q1  = *(const float4*)&Qs[i0 + 1][kk * 4];
            const float4 k0v = *(const float4*)&Buf[j0 + 0][kk * 4];
            const float4 k1v = *(const float4*)&Buf[j0 + 1][kk * 4];
            const float4 k2v = *(const float4*)&Buf[j0 + 2][kk * 4];
            const float4 k3v = *(const float4*)&Buf[j0 + 3][kk * 4];
            a00 += q0.x*k0v.x + q0.y*k0v.y + q0.z*k0v.z + q0.w*k0v.w;
            a01 += q0.x*k1v.x + q0.y*k1v.y + q0.z*k1v.z + q0.w*k1v.w;
            a02 += q0.x*k2v.x + q0.y*k2v.y + q0.z*k2v.z + q0.w*k2v.w;
            a03 += q0.x*k3v.x + q0.y*k3v.y + q0.z*k3v.z + q0.w*k3v.w;
            a10 += q1.x*k0v.x + q1.y*k0v.y + q1.z*k0v.z + q1.w*k0v.w;
            a11 += q1.x*k1v.x + q1.y*k1v.y + q1.z*k1v.z + q1.w*k1v.w;
            a12 += q1.x*k2v.x + q1.y*k2v.y + q1.z*k2v.z + q1.w*k2v.w;
            a13 += q1.x*k3v.x + q1.y*k3v.y + q1.z*k3v.z + q1.w*k3v.w;
        }
        const float scale = 0.088388347648318447f;  // 128^-0.5
        Sm[i0    ][j0+0] = a00*scale; Sm[i0    ][j0+1] = a01*scale;
        Sm[i0    ][j0+2] = a02*scale; Sm[i0    ][j0+3] = a03*scale;
        Sm[i0 + 1][j0+0] = a10*scale; Sm[i0 + 1][j0+1] = a11*scale;
        Sm[i0 + 1][j0+2] = a12*scale; Sm[i0 + 1][j0+3] = a13*scale;
    }
    __syncthreads();

    // start V load (overwrites Buf — scores phase is done) ...
    for (int idx = tid; idx < 96 * 32; idx += 256) {
        const int n = idx >> 5, dv = idx & 31;
        const int g = (n < 16) ? (s * 16 + n) : (128 + s * 80 + (n - 16));
        *(float4*)&Buf[n][dv * 4] =
            *(const float4*)(KV + (size_t)g * 1536 + 768 + h * 128 + dv * 4);
    }
    // ... while doing row softmax (global-max shift in ref cancels; per-row max is exact)
    {
        const int i = tid >> 4, l = tid & 15;
        const float v0 = Sm[i][l],      v1 = Sm[i][l + 16], v2 = Sm[i][l + 32],
                    v3 = Sm[i][l + 48], v4 = Sm[i][l + 64], v5 = Sm[i][l + 80];
        float m = fmaxf(fmaxf(fmaxf(v0, v1), fmaxf(v2, v3)), fmaxf(v4, v5));
        #pragma unroll
        for (int o = 8; o >= 1; o >>= 1) m = fmaxf(m, __shfl_xor(m, o, 16));
        const float e0 = __expf(v0 - m), e1 = __expf(v1 - m), e2 = __expf(v2 - m),
                    e3 = __expf(v3 - m), e4 = __expf(v4 - m), e5 = __expf(v5 - m);
        float sum = e0 + e1 + e2 + e3 + e4 + e5;
        #pragma unroll
        for (int o = 8; o >= 1; o >>= 1) sum += __shfl_xor(sum, o, 16);
        const float inv = 1.0f / sum;
        Sm[i][l]      = e0 * inv; Sm[i][l + 16] = e1 * inv; Sm[i][l + 32] = e2 * inv;
        Sm[i][l + 48] = e3 * inv; Sm[i][l + 64] = e4 * inv; Sm[i][l + 80] = e5 * inv;
    }
    __syncthreads();

    // O = P @ V
    {
        const int i = tid >> 4, dv = tid & 15;
        float4 o0 = make_float4(0, 0, 0, 0), o1 = make_float4(0, 0, 0, 0);
        #pragma unroll 4
        for (int j = 0; j < 96; ++j) {
            const float p = Sm[i][j];
            const float4 va = *(const float4*)&Buf[j][dv * 4];
            const float4 vb = *(const float4*)&Buf[j][64 + dv * 4];
            o0.x += p * va.x; o0.y += p * va.y; o0.z += p * va.z; o0.w += p * va.w;
            o1.x += p * vb.x; o1.y += p * vb.y; o1.z += p * vb.z; o1.w += p * vb.w;
        }
        float* dst = AO + (size_t)(s * 16 + i) * 768 + h * 128;
        *(float4*)(dst + dv * 4)      = o0;
        *(float4*)(dst + 64 + dv * 4) = o1;
    }
}

// ---------------------------------------------------------------------------
// Kernel 3: per-agent epilogue. 128 blocks x 256 threads.
__global__ __launch_bounds__(256) void k_final(
    const float* __restrict__ AO, const float* __restrict__ agents,
    const float* __restrict__ Wout1, const float* __restrict__ Wout2,
    const float* __restrict__ W1, const float* __restrict__ ln_g,
    const float* __restrict__ ln_b, const float* __restrict__ W2,
    float* __restrict__ out)
{
    const int a = blockIdx.x;
    const int tid = threadIdx.x;
    __shared__ float x[768];
    __shared__ float nrow[128];
    __shared__ float ps[256];
    __shared__ float y1[128];
    __shared__ float y2[128];
    __shared__ float basev[128];
    __shared__ float hbuf[128];
    __shared__ float red[4];

    if (tid < 192) {
        *(float4*)&x[tid * 4] = *(const float4*)(AO + (size_t)a * 768 + tid * 4);
    } else if (tid < 224) {
        const int q = tid - 192;
        *(float4*)&nrow[q * 4] = *(const float4*)(agents + (size_t)a * 128 + q * 4);
    }
    __syncthreads();

    // y1 = relu(x @ Wout1), split-k over 2 halves of 384
    {
        const int d = tid & 127, half = tid >> 7;
        const int k0 = half * 384;
        float p = 0.f;
        #pragma unroll 4
        for (int k = 0; k < 384; ++k)
            p += x[k0 + k] * Wout1[(size_t)(k0 + k) * 128 + d];
        ps[tid] = p;
    }
    __syncthreads();
    if (tid < 128) y1[tid] = fmaxf(ps[tid] + ps[tid + 128], 0.0f);
    __syncthreads();

    // y2 = y1 @ Wout2 (threads 0..127); base = nodes_row @ W1 (threads 128..255)
    if (tid < 128) {
        float p = 0.f;
        #pragma unroll 4
        for (int k = 0; k < 128; ++k) p += y1[k] * Wout2[k * 128 + tid];
        y2[tid] = p;
    } else {
        const int d = tid - 128;
        float p = 0.f;
        #pragma unroll 4
        for (int k = 0; k < 128; ++k) p += nrow[k] * W1[k * 128 + d];
        basev[d] = p;
    }
    __syncthreads();

    // LayerNorm over t = base + y2 (threads 0..127 span 2 waves)
    float tval = 0.f;
    if (tid < 128) tval = basev[tid] + y2[tid];
    float s1 = tval, s2 = tval * tval;
    #pragma unroll
    for (int o = 32; o >= 1; o >>= 1) { s1 += __shfl_xor(s1, o); s2 += __shfl_xor(s2, o); }
    if (tid < 128 && (tid & 63) == 0) { red[(tid >> 6) * 2] = s1; red[(tid >> 6) * 2 + 1] = s2; }
    __syncthreads();
    if (tid < 128) {
        const float S1 = red[0] + red[2], S2 = red[1] + red[3];
        const float mu  = S1 * (1.0f / 128.0f);
        const float var = S2 * (1.0f / 128.0f) - mu * mu;
        const float rinv = rsqrtf(var + LN_EPS);
        const float hv = (tval - mu) * rinv * ln_g[tid] + ln_b[tid];
        hbuf[tid] = fmaxf(hv, 0.0f);
    }
    __syncthreads();
    if (tid < 128) {
        float p = 0.f;
        #pragma unroll 4
        for (int k = 0; k < 128; ++k) p += hbuf[k] * W2[k * 128 + tid];
        out[(size_t)a * 128 + tid] = fmaxf(p + nrow[tid], 0.0f);
    }
}

// ---------------------------------------------------------------------------
extern "C" void kernel_launch(void* const* d_in, const int* in_sizes, int n_in,
                              void* d_out, int out_size, void* d_ws, size_t ws_size,
                              hipStream_t stream)
{
    const float* agents = (const float*)d_in[0];
    const float* lanes  = (const float*)d_in[1];
    const float* Wq     = (const float*)d_in[2];
    const float* Wk     = (const float*)d_in[3];
    const float* Wv     = (const float*)d_in[4];
    const float* Wout1  = (const float*)d_in[5];
    const float* Wout2  = (const float*)d_in[6];
    const float* W1     = (const float*)d_in[7];
    const float* ln_g   = (const float*)d_in[8];
    const float* ln_b   = (const float*)d_in[9];
    const float* W2     = (const float*)d_in[10];
    // d_in[11], d_in[12] = hi, wi — edge structure is static (dense per scene), unused.

    float* ws = (float*)d_ws;
    float* KV = ws;                         // [768][1536]
    float* Qb = KV + 768 * 1536;            // [128][768]
    float* AO = Qb + 128 * 768;             // [128][768]
    float* outp = (float*)d_out;

    k_gemm_qkv<<<156, 256, 0, stream>>>(agents, lanes, Wq, Wk, Wv, KV, Qb);
    k_attn<<<48, 256, 0, stream>>>(KV, Qb, AO);
    k_final<<<128, 256, 0, stream>>>(AO, agents, Wout1, Wout2, W1, ln_g, ln_b, W2, outp);
}

// Round 2
// 123.430 us; speedup vs baseline: 1.3039x; 1.3039x over previous
//
#include <hip/hip_runtime.h>
#include <math.h>

#define LN_EPS 1e-5f

// Problem: B=8 scenes, A=16 agents, L=80 lanes, D=128, H=6.
// N=768 nodes (128 agents first), 96 nodes/scene, dense per-scene attention.
// ws layout (floats): KV[768][1536] | Qb[128][768] | AO[128][768]
// y1pre[128][128] aliases Qb (dead after k_attn).

// ---------------------------------------------------------------------------
// Kernel 1: KV = nodes @ [Wk | Wv(relu)] , Qb = agents @ Wq
// 64 rows x 128 cols per block, 256 threads, 4x8 per thread.
// A transposed in LDS; B staged in 32-k chunks with register prefetch.
__global__ __launch_bounds__(256) void k_gemm_qkv(
    const float* __restrict__ agents, const float* __restrict__ lanes,
    const float* __restrict__ Wq, const float* __restrict__ Wk,
    const float* __restrict__ Wv, float* __restrict__ KV, float* __restrict__ Qb)
{
    __shared__ float Ast[128][64];   // [k][row] 32 KB
    __shared__ float Bst[32][128];   // [k][col] 16 KB

    const int tid = threadIdx.x;
    const int bid = blockIdx.x;

    const float* W;
    float* Out;
    int r0, wc0, dc0, dstride;
    bool dorelu = false;
    if (bid < 144) {                       // KV: 12 row-blocks x 12 col-blocks
        const int br = bid % 12, bc = bid / 12;
        r0 = br * 64;
        if (bc < 6) { W = Wk; wc0 = bc * 128; }
        else        { W = Wv; wc0 = (bc - 6) * 128; dorelu = true; }
        Out = KV; dc0 = bc * 128; dstride = 1536;
    } else {                               // Q: 2 row-blocks x 6 col-blocks
        const int idx = bid - 144;
        r0 = (idx & 1) * 64;
        W = Wq; wc0 = (idx >> 1) * 128;
        Out = Qb; dc0 = wc0; dstride = 768;
    }

    // stage A tile (64 rows x 128 k), transposed into Ast[k][row]
    {
        const int row = tid >> 2;      // 0..63
        const int kv = tid & 3;        // 0..3
        const int gr = r0 + row;
        const float* src = (gr < 128) ? (agents + gr * 128)
                                      : (lanes + (size_t)(gr - 128) * 128);
        #pragma unroll
        for (int j = 0; j < 8; ++j) {
            const int k0 = kv * 4 + j * 16;
            const float4 a = *(const float4*)(src + k0);
            Ast[k0 + 0][row] = a.x; Ast[k0 + 1][row] = a.y;
            Ast[k0 + 2][row] = a.z; Ast[k0 + 3][row] = a.w;
        }
    }

    // prefetch B chunk 0 into registers: chunk = 32 k-rows x 128 cols
    const int pk = tid >> 5;   // 0..7 (+8 per i)
    const int pc = tid & 31;   // float4 col index
    const float* wbase = W + wc0 + 4 * pc;
    float4 pre[4];
    #pragma unroll
    for (int i = 0; i < 4; ++i)
        pre[i] = *(const float4*)(wbase + (size_t)(pk + 8 * i) * 768);

    __syncthreads();

    const int tx = tid & 15;    // cols 4tx..4tx+3 and 64+4tx..64+4tx+3
    const int ty = tid >> 4;    // rows 4ty..4ty+3
    float acc[4][8] = {};

    for (int kc = 0; kc < 4; ++kc) {
        #pragma unroll
        for (int i = 0; i < 4; ++i)
            *(float4*)&Bst[pk + 8 * i][4 * pc] = pre[i];
        __syncthreads();
        if (kc < 3) {
            const float* wn = wbase + (size_t)(kc + 1) * 32 * 768;
            #pragma unroll
            for (int i = 0; i < 4; ++i)
                pre[i] = *(const float4*)(wn + (size_t)(pk + 8 * i) * 768);
        }
        #pragma unroll 8
        for (int kk = 0; kk < 32; ++kk) {
            const float4 a  = *(const float4*)&Ast[kc * 32 + kk][ty * 4];
            const float4 b0 = *(const float4*)&Bst[kk][tx * 4];
            const float4 b1 = *(const float4*)&Bst[kk][64 + tx * 4];
            const float av[4] = {a.x, a.y, a.z, a.w};
            #pragma unroll
            for (int i = 0; i < 4; ++i) {
                acc[i][0] += av[i] * b0.x; acc[i][1] += av[i] * b0.y;
                acc[i][2] += av[i] * b0.z; acc[i][3] += av[i] * b0.w;
                acc[i][4] += av[i] * b1.x; acc[i][5] += av[i] * b1.y;
                acc[i][6] += av[i] * b1.z; acc[i][7] += av[i] * b1.w;
            }
        }
        __syncthreads();
    }

    #pragma unroll
    for (int i = 0; i < 4; ++i) {
        const int r = r0 + ty * 4 + i;
        float v[8];
        #pragma unroll
        for (int c = 0; c < 8; ++c) v[c] = dorelu ? fmaxf(acc[i][c], 0.0f) : acc[i][c];
        float* dst = Out + (size_t)r * dstride + dc0;
        *(float4*)(dst + tx * 4)      = make_float4(v[0], v[1], v[2], v[3]);
        *(float4*)(dst + 64 + tx * 4) = make_float4(v[4], v[5], v[6], v[7]);
    }
}

// ---------------------------------------------------------------------------
// Kernel 2: per (scene, head) attention. 48 blocks x 256 threads.
// Padded LDS rows kill the 512B-stride bank aliasing of R1.
__global__ __launch_bounds__(256) void k_attn(
    const float* __restrict__ KV, const float* __restrict__ Qb, float* __restrict__ AO)
{
    __shared__ float Qs[16][132];
    __shared__ float Buf[96][132];   // K, then reused for V
    __shared__ float Sm[16][100];

    const int tid = threadIdx.x;
    const int s = blockIdx.x / 6;
    const int h = blockIdx.x % 6;

    for (int idx = tid; idx < 16 * 32; idx += 256) {
        const int i = idx >> 5, dv = idx & 31;
        *(float4*)&Qs[i][dv * 4] =
            *(const float4*)(Qb + (size_t)(s * 16 + i) * 768 + h * 128 + dv * 4);
    }
    for (int idx = tid; idx < 96 * 32; idx += 256) {
        const int n = idx >> 5, dv = idx & 31;
        const int g = (n < 16) ? (s * 16 + n) : (128 + s * 80 + (n - 16));
        *(float4*)&Buf[n][dv * 4] =
            *(const float4*)(KV + (size_t)g * 1536 + h * 128 + dv * 4);
    }
    __syncthreads();

    // scores: thread -> rows {i0,i0+1}, cols {jc, jc+32, jc+64}
    {
        const int i0 = (tid >> 5) * 2, jc = tid & 31;
        float s00 = 0, s01 = 0, s02 = 0, s10 = 0, s11 = 0, s12 = 0;
        #pragma unroll 4
        for (int kk = 0; kk < 32; ++kk) {
            const float4 q0 = *(const float4*)&Qs[i0][kk * 4];
            const float4 q1 = *(const float4*)&Qs[i0 + 1][kk * 4];
            const float4 b0 = *(const float4*)&Buf[jc][kk * 4];
            const float4 b1 = *(const float4*)&Buf[jc + 32][kk * 4];
            const float4 b2 = *(const float4*)&Buf[jc + 64][kk * 4];
            s00 += q0.x*b0.x + q0.y*b0.y + q0.z*b0.z + q0.w*b0.w;
            s01 += q0.x*b1.x + q0.y*b1.y + q0.z*b1.z + q0.w*b1.w;
            s02 += q0.x*b2.x + q0.y*b2.y + q0.z*b2.z + q0.w*b2.w;
            s10 += q1.x*b0.x + q1.y*b0.y + q1.z*b0.z + q1.w*b0.w;
            s11 += q1.x*b1.x + q1.y*b1.y + q1.z*b1.z + q1.w*b1.w;
            s12 += q1.x*b2.x + q1.y*b2.y + q1.z*b2.z + q1.w*b2.w;
        }
        const float scale = 0.088388347648318447f;  // 128^-0.5
        Sm[i0][jc]          = s00 * scale;
        Sm[i0][jc + 32]     = s01 * scale;
        Sm[i0][jc + 64]     = s02 * scale;
        Sm[i0 + 1][jc]      = s10 * scale;
        Sm[i0 + 1][jc + 32] = s11 * scale;
        Sm[i0 + 1][jc + 64] = s12 * scale;
    }
    __syncthreads();

    // V load (overwrites Buf) overlapped with softmax on Sm
    for (int idx = tid; idx < 96 * 32; idx += 256) {
        const int n = idx >> 5, dv = idx & 31;
        const int g = (n < 16) ? (s * 16 + n) : (128 + s * 80 + (n - 16));
        *(float4*)&Buf[n][dv * 4] =
            *(const float4*)(KV + (size_t)g * 1536 + 768 + h * 128 + dv * 4);
    }
    {
        const int i = tid >> 4, l = tid & 15;
        const float v0 = Sm[i][l],      v1 = Sm[i][l + 16], v2 = Sm[i][l + 32],
                    v3 = Sm[i][l + 48], v4 = Sm[i][l + 64], v5 = Sm[i][l + 80];
        float m = fmaxf(fmaxf(fmaxf(v0, v1), fmaxf(v2, v3)), fmaxf(v4, v5));
        #pragma unroll
        for (int o = 8; o >= 1; o >>= 1) m = fmaxf(m, __shfl_xor(m, o, 16));
        const float e0 = __expf(v0 - m), e1 = __expf(v1 - m), e2 = __expf(v2 - m),
                    e3 = __expf(v3 - m), e4 = __expf(v4 - m), e5 = __expf(v5 - m);
        float sum = e0 + e1 + e2 + e3 + e4 + e5;
        #pragma unroll
        for (int o = 8; o >= 1; o >>= 1) sum += __shfl_xor(sum, o, 16);
        const float inv = 1.0f / sum;
        Sm[i][l]      = e0 * inv; Sm[i][l + 16] = e1 * inv; Sm[i][l + 32] = e2 * inv;
        Sm[i][l + 48] = e3 * inv; Sm[i][l + 64] = e4 * inv; Sm[i][l + 80] = e5 * inv;
    }
    __syncthreads();

    // O = P @ V
    {
        const int i = tid >> 4, dv = tid & 15;
        float4 o0 = make_float4(0, 0, 0, 0), o1 = make_float4(0, 0, 0, 0);
        #pragma unroll 4
        for (int j = 0; j < 96; ++j) {
            const float p = Sm[i][j];
            const float4 va = *(const float4*)&Buf[j][dv * 4];
            const float4 vb = *(const float4*)&Buf[j][64 + dv * 4];
            o0.x += p * va.x; o0.y += p * va.y; o0.z += p * va.z; o0.w += p * va.w;
            o1.x += p * vb.x; o1.y += p * vb.y; o1.z += p * vb.z; o1.w += p * vb.w;
        }
        float* dst = AO + (size_t)(s * 16 + i) * 768 + h * 128;
        *(float4*)(dst + dv * 4)      = o0;
        *(float4*)(dst + 64 + dv * 4) = o1;
    }
}

// ---------------------------------------------------------------------------
// Kernel 3a: y1pre = AO @ Wout1 (pre-relu), tiled GEMM with K-split + atomics.
// Grid 48 = 4(M/32) x 2(N/64) x 6(K/128). 256 threads, 2x4 per thread.
__global__ __launch_bounds__(256) void k_f1(
    const float* __restrict__ AO, const float* __restrict__ Wout1,
    float* __restrict__ y1pre)
{
    __shared__ float Ash[128][32];  // [k][m] 16 KB
    __shared__ float Bsh[128][64];  // [k][n] 32 KB

    const int tid = threadIdx.x;
    const int b = blockIdx.x;
    const int mb = b & 3, nb = (b >> 2) & 1, kb = b >> 3;
    const int m0 = mb * 32, n0 = nb * 64, k0 = kb * 128;

    // stage A transposed: 32 rows x 128 k
    {
        const int row = tid & 31, c4b = tid >> 5;   // c4b 0..7
        #pragma unroll
        for (int i = 0; i < 4; ++i) {
            const int cc = c4b + 8 * i;             // float4 index along k (0..31)
            const float4 a = *(const float4*)(AO + (size_t)(m0 + row) * 768 + k0 + cc * 4);
            Ash[cc * 4 + 0][row] = a.x; Ash[cc * 4 + 1][row] = a.y;
            Ash[cc * 4 + 2][row] = a.z; Ash[cc * 4 + 3][row] = a.w;
        }
    }
    // stage B: 128 k x 64 n, coalesced
    {
        const int kr = tid >> 4, c4 = tid & 15;
        #pragma unroll
        for (int i = 0; i < 8; ++i) {
            const int k = kr + 16 * i;
            *(float4*)&Bsh[k][c4 * 4] =
                *(const float4*)(Wout1 + (size_t)(k0 + k) * 128 + n0 + c4 * 4);
        }
    }
    __syncthreads();

    const int tx = tid & 15;   // cols 4tx..4tx+3
    const int ty = tid >> 4;   // rows 2ty..2ty+1
    float acc[2][4] = {};
    #pragma unroll 8
    for (int k = 0; k < 128; ++k) {
        const float2 a = *(const float2*)&Ash[k][ty * 2];
        const float4 bv = *(const float4*)&Bsh[k][tx * 4];
        acc[0][0] += a.x * bv.x; acc[0][1] += a.x * bv.y;
        acc[0][2] += a.x * bv.z; acc[0][3] += a.x * bv.w;
        acc[1][0] += a.y * bv.x; acc[1][1] += a.y * bv.y;
        acc[1][2] += a.y * bv.z; acc[1][3] += a.y * bv.w;
    }
    #pragma unroll
    for (int r = 0; r < 2; ++r)
        #pragma unroll
        for (int c = 0; c < 4; ++c)
            atomicAdd(&y1pre[(size_t)(m0 + ty * 2 + r) * 128 + n0 + tx * 4 + c],
                      acc[r][c]);
}

// ---------------------------------------------------------------------------
// Kernel 3b: per-agent epilogue, 128 blocks x 512 threads, 4-way split-k GEMVs.
__global__ __launch_bounds__(512) void k_f2(
    const float* __restrict__ y1pre, const float* __restrict__ agents,
    const float* __restrict__ Wout2, const float* __restrict__ W1,
    const float* __restrict__ ln_g, const float* __restrict__ ln_b,
    const float* __restrict__ W2, float* __restrict__ out)
{
    const int a = blockIdx.x;
    const int tid = threadIdx.x;
    __shared__ float y1[128];
    __shared__ float nrow[128];
    __shared__ float hbuf[128];
    __shared__ float ps[512];
    __shared__ float red[4];

    if (tid < 32) {
        const float4 v = *(const float4*)(y1pre + (size_t)a * 128 + tid * 4);
        y1[tid * 4 + 0] = fmaxf(v.x, 0.f); y1[tid * 4 + 1] = fmaxf(v.y, 0.f);
        y1[tid * 4 + 2] = fmaxf(v.z, 0.f); y1[tid * 4 + 3] = fmaxf(v.w, 0.f);
    } else if (tid < 64) {
        const int t = tid - 32;
        *(float4*)&nrow[t * 4] = *(const float4*)(agents + (size_t)a * 128 + t * 4);
    }
    __syncthreads();

    const int d = tid & 127, g = tid >> 7;   // g: 0,1 -> y2 halves; 2,3 -> base halves
    {
        const float* src = (g < 2) ? y1 : nrow;
        const float* Wm  = (g < 2) ? Wout2 : W1;
        const int k0 = (g & 1) * 64;
        float p = 0.f;
        #pragma unroll 8
        for (int k = 0; k < 64; ++k)
            p += src[k0 + k] * Wm[(size_t)(k0 + k) * 128 + d];
        ps[tid] = p;
    }
    __syncthreads();

    // t = base + y2 ; LayerNorm over 128 (threads 0..127 in waves 0,1)
    float tval = 0.f;
    if (tid < 128) tval = ps[d] + ps[128 + d] + ps[256 + d] + ps[384 + d];
    float s1 = tval, s2 = tval * tval;
    #pragma unroll
    for (int o = 32; o >= 1; o >>= 1) { s1 += __shfl_xor(s1, o); s2 += __shfl_xor(s2, o); }
    if (tid < 128 && (tid & 63) == 0) {
        red[(tid >> 6) * 2] = s1; red[(tid >> 6) * 2 + 1] = s2;
    }
    __syncthreads();
    if (tid < 128) {
        const float S1 = red[0] + red[2], S2 = red[1] + red[3];
        const float mu  = S1 * (1.0f / 128.0f);
        const float var = S2 * (1.0f / 128.0f) - mu * mu;
        const float rin = rsqrtf(var + LN_EPS);
        hbuf[tid] = fmaxf((tval - mu) * rin * ln_g[tid] + ln_b[tid], 0.0f);
    }
    __syncthreads();

    {
        const int k0 = g * 32;
        float p = 0.f;
        #pragma unroll 8
        for (int k = 0; k < 32; ++k)
            p += hbuf[k0 + k] * W2[(size_t)(k0 + k) * 128 + d];
        ps[tid] = p;
    }
    __syncthreads();
    if (tid < 128)
        out[(size_t)a * 128 + d] =
            fmaxf(ps[d] + ps[128 + d] + ps[256 + d] + ps[384 + d] + nrow[d], 0.0f);
}

// ---------------------------------------------------------------------------
extern "C" void kernel_launch(void* const* d_in, const int* in_sizes, int n_in,
                              void* d_out, int out_size, void* d_ws, size_t ws_size,
                              hipStream_t stream)
{
    const float* agents = (const float*)d_in[0];
    const float* lanes  = (const float*)d_in[1];
    const float* Wq     = (const float*)d_in[2];
    const float* Wk     = (const float*)d_in[3];
    const float* Wv     = (const float*)d_in[4];
    const float* Wout1  = (const float*)d_in[5];
    const float* Wout2  = (const float*)d_in[6];
    const float* W1     = (const float*)d_in[7];
    const float* ln_g   = (const float*)d_in[8];
    const float* ln_b   = (const float*)d_in[9];
    const float* W2     = (const float*)d_in[10];
    // d_in[11], d_in[12] = hi, wi — static dense per-scene structure, unused.

    float* ws = (float*)d_ws;
    float* KV    = ws;                     // [768][1536]
    float* Qb    = KV + 768 * 1536;        // [128][768]
    float* AO    = Qb + 128 * 768;         // [128][768]
    float* y1pre = Qb;                     // [128][128] aliases Qb (dead after k_attn)
    float* outp  = (float*)d_out;

    k_gemm_qkv<<<156, 256, 0, stream>>>(agents, lanes, Wq, Wk, Wv, KV, Qb);
    k_attn<<<48, 256, 0, stream>>>(KV, Qb, AO);
    hipMemsetAsync(y1pre, 0, 128 * 128 * sizeof(float), stream);
    k_f1<<<48, 256, 0, stream>>>(AO, Wout1, y1pre);
    k_f2<<<128, 512, 0, stream>>>(y1pre, agents, Wout2, W1, ln_g, ln_b, W2, outp);
}